// Round 7
// baseline (1217.547 us; speedup 1.0000x reference)
//
#include <hip/hip_runtime.h>

// VQ-VAE quantizer, MI355X (gfx950). Round 7: bit-exact np emulation (passing
// since r5), proj rewritten: packed-f32 (v_pk_mul/add, identical IEEE RN),
// 4-outputs-per-lane register tiling, 1-wave blocks, tiny LDS f-staging.
// argmin/transpose/rescan/gather/loss identical to round 6 (PASS).

typedef _Float16 f16;
typedef _Float16 half8 __attribute__((ext_vector_type(8)));
typedef float floatx4 __attribute__((ext_vector_type(4)));
typedef float float2v __attribute__((ext_vector_type(2)));

#define ROWS   32768
#define IN_DIM 1024
#define DDIM   256
#define KEMB   4096
#define TAU    0.10f
#define RSB    8
#define PRJ_R  8

__device__ __forceinline__ float fmul(float a, float b) { return __fmul_rn(a, b); }
__device__ __forceinline__ float fadd(float a, float b) { return __fadd_rn(a, b); }

// packed f32 ops: element-wise IEEE round-to-nearest, bit-identical to
// v_mul_f32 / v_add_f32 per component; asm blocks any reassociation.
__device__ __forceinline__ float2v pk_mul2(float2v a, float2v b) {
    float2v d;
    asm("v_pk_mul_f32 %0, %1, %2" : "=v"(d) : "v"(a), "v"(b));
    return d;
}
__device__ __forceinline__ float2v pk_add2(float2v a, float2v b) {
    float2v d;
    asm("v_pk_add_f32 %0, %1, %2" : "=v"(d) : "v"(a), "v"(b));
    return d;
}

__device__ __forceinline__ void split2(float x, f16& hi, f16& lo) {
    float h = (float)(f16)x;
    if (__builtin_fabsf(h) < 6.1035156e-5f) h = 0.0f;
    hi = (f16)h;
    lo = (f16)((x - h) * 2048.0f);
}

// np.sum(x*x) over 256 f32: pairwise 128+128; AVX512 vstep=16 block tree.
__device__ float np_sumsq_256(const float* __restrict__ x) {
    float blk[2];
    #pragma unroll
    for (int h = 0; h < 2; ++h) {
        const float* p = x + h * 128;
        float s[16];
        #pragma unroll
        for (int l = 0; l < 16; ++l) {
            float q0 = fmul(p[l],       p[l]);
            float q1 = fmul(p[16 + l],  p[16 + l]);
            float q2 = fmul(p[32 + l],  p[32 + l]);
            float q3 = fmul(p[48 + l],  p[48 + l]);
            float q4 = fmul(p[64 + l],  p[64 + l]);
            float q5 = fmul(p[80 + l],  p[80 + l]);
            float q6 = fmul(p[96 + l],  p[96 + l]);
            float q7 = fmul(p[112 + l], p[112 + l]);
            s[l] = fadd(fadd(fadd(q0, q1), fadd(q2, q3)),
                        fadd(fadd(q4, q5), fadd(q6, q7)));
        }
        float t1[8];
        #pragma unroll
        for (int l = 0; l < 8; ++l) t1[l] = fadd(s[l], s[l + 8]);
        float t2[4];
        #pragma unroll
        for (int l = 0; l < 4; ++l) t2[l] = fadd(t1[l], t1[l + 4]);
        blk[h] = fadd(fadd(t2[0], t2[2]), fadd(t2[1], t2[3]));
    }
    return fadd(blk[0], blk[1]);
}

// ---------------------------------------------------------------- K1: prep
__global__ __launch_bounds__(256) void vq_prep_codebook(
    const float* __restrict__ cb, f16* __restrict__ chi, f16* __restrict__ clo,
    float* __restrict__ cn3)
{
    int k = blockIdx.x;
    int d = threadIdx.x;
    float c = cb[(size_t)k * DDIM + d] * 4096.0f;
    f16 hi, lo;
    split2(c, hi, lo);
    chi[(size_t)k * DDIM + d] = hi;
    clo[(size_t)k * DDIM + d] = lo;
    float sq = c * c;
    #pragma unroll
    for (int off = 32; off > 0; off >>= 1) sq += __shfl_down(sq, off);
    __shared__ float red[4];
    if ((threadIdx.x & 63) == 0) red[threadIdx.x >> 6] = sq;
    __syncthreads();
    if (threadIdx.x == 0)
        cn3[k] = (red[0] + red[1] + red[2] + red[3]) * (1.0f / 8192.0f);
}

// ---------------------------------------------------------------- K2: proj (np.einsum emu, packed)
// 64-thread blocks; lane owns d = lane + {0,64,128,192}; 8 rows/block.
// Same rounding sequence as round 5/6: per 16-float chunk, subchunk order
// 3,2,1,0; per-component sequential adds; hsum (x+y)+(z+w); then +bias.
__global__ __launch_bounds__(64, 2) void vq_proj_np(
    const float* __restrict__ feat, const float* __restrict__ Wm,
    const float* __restrict__ bias, float* __restrict__ pf)
{
    __shared__ float fs[PRJ_R][68];
    const int r0 = blockIdx.x * PRJ_R;
    const int lane = threadIdx.x;

    float2v accA[4][PRJ_R], accB[4][PRJ_R];
    #pragma unroll
    for (int q = 0; q < 4; ++q)
        #pragma unroll
        for (int r = 0; r < PRJ_R; ++r) {
            accA[q][r] = (float2v){0.f, 0.f};
            accB[q][r] = (float2v){0.f, 0.f};
        }

    const float* wp0 = Wm + (size_t)(lane      ) * IN_DIM;
    const float* wp1 = Wm + (size_t)(lane +  64) * IN_DIM;
    const float* wp2 = Wm + (size_t)(lane + 128) * IN_DIM;
    const float* wp3 = Wm + (size_t)(lane + 192) * IN_DIM;

    for (int g = 0; g < IN_DIM / 64; ++g) {
        __syncthreads();   // WAR: previous group's reads done
        {
            int r = lane >> 3, k8 = (lane & 7) * 8;
            const float4* src = (const float4*)(feat + (size_t)(r0 + r) * IN_DIM + g * 64 + k8);
            float4 v0 = src[0], v1 = src[1];
            *(float4*)&fs[r][k8]     = v0;
            *(float4*)&fs[r][k8 + 4] = v1;
        }
        __syncthreads();

        #pragma unroll 1
        for (int sub = 0; sub < 4; ++sub) {
            #pragma unroll
            for (int jj = 0; jj < 4; ++jj) {
                const int j = 3 - jj;                    // np einsum cascade order
                const int ko = g * 64 + sub * 16 + j * 4;
                float4 w0 = *(const float4*)(wp0 + ko);
                float4 w1 = *(const float4*)(wp1 + ko);
                float4 w2 = *(const float4*)(wp2 + ko);
                float4 w3 = *(const float4*)(wp3 + ko);
                float2v w0a = {w0.x, w0.y}, w0b = {w0.z, w0.w};
                float2v w1a = {w1.x, w1.y}, w1b = {w1.z, w1.w};
                float2v w2a = {w2.x, w2.y}, w2b = {w2.z, w2.w};
                float2v w3a = {w3.x, w3.y}, w3b = {w3.z, w3.w};
                #pragma unroll
                for (int r = 0; r < PRJ_R; ++r) {
                    float4 fv = *(const float4*)&fs[r][sub * 16 + j * 4];
                    float2v fa = {fv.x, fv.y}, fb = {fv.z, fv.w};
                    accA[0][r] = pk_add2(accA[0][r], pk_mul2(fa, w0a));
                    accB[0][r] = pk_add2(accB[0][r], pk_mul2(fb, w0b));
                    accA[1][r] = pk_add2(accA[1][r], pk_mul2(fa, w1a));
                    accB[1][r] = pk_add2(accB[1][r], pk_mul2(fb, w1b));
                    accA[2][r] = pk_add2(accA[2][r], pk_mul2(fa, w2a));
                    accB[2][r] = pk_add2(accB[2][r], pk_mul2(fb, w2b));
                    accA[3][r] = pk_add2(accA[3][r], pk_mul2(fa, w3a));
                    accB[3][r] = pk_add2(accB[3][r], pk_mul2(fb, w3b));
                }
            }
        }
    }

    float bv[4] = { bias[lane], bias[lane + 64], bias[lane + 128], bias[lane + 192] };
    #pragma unroll
    for (int q = 0; q < 4; ++q)
        #pragma unroll
        for (int r = 0; r < PRJ_R; ++r) {
            float h = fadd(fadd(accA[q][r][0], accA[q][r][1]),
                           fadd(accB[q][r][0], accB[q][r][1]));
            pf[(size_t)(r0 + r) * DDIM + lane + q * 64] = fadd(h, bv[q]);
        }
}

// ---------------------------------------------------------------- K3: MFMA argmin filter (2-pass)
__global__ __launch_bounds__(256) void vq_argmin(
    const float* __restrict__ pf,
    const f16* __restrict__ chi, const f16* __restrict__ clo,
    const float* __restrict__ cn3, int* __restrict__ out_idx,
    int* __restrict__ fs_cnt, int* __restrict__ fs_list)
{
    __shared__ f16 PH[64][72], CH[128][72], CL[128][72];
    __shared__ float mV1[64][2], mV2[64][2];
    __shared__ int   mI1[64][2];
    const int m0 = blockIdx.x * 64;
    const int tid = threadIdx.x;
    const int lane = tid & 63;
    const int w = tid >> 6;
    const int wr = w >> 1, wc = w & 1;

    float v1[8], v2[8];
    int i1[8];
    #pragma unroll
    for (int s = 0; s < 8; ++s) { v1[s] = -__builtin_inff(); v2[s] = -__builtin_inff(); i1[s] = 0; }

    for (int nt = 0; nt < KEMB / 128; ++nt) {
        floatx4 acc1[2][4], acc2[2][4];
        #pragma unroll
        for (int mi = 0; mi < 2; ++mi)
            #pragma unroll
            for (int ni = 0; ni < 4; ++ni) {
                acc1[mi][ni] = (floatx4){0.f, 0.f, 0.f, 0.f};
                acc2[mi][ni] = (floatx4){0.f, 0.f, 0.f, 0.f};
            }

        for (int ks = 0; ks < 4; ++ks) {
            { // stage P [64][64] hi-only, split on the fly
                int r = tid >> 2, q = (tid & 3) * 16;
                const float4* s4 = (const float4*)(pf + (size_t)(m0 + r) * DDIM + ks * 64 + q);
                f16 th[16];
                #pragma unroll
                for (int i = 0; i < 4; ++i) {
                    float4 v = s4[i];
                    f16 dead;
                    split2(v.x, th[4*i+0], dead);
                    split2(v.y, th[4*i+1], dead);
                    split2(v.z, th[4*i+2], dead);
                    split2(v.w, th[4*i+3], dead);
                }
                *(half8*)&PH[r][q]     = *(half8*)&th[0];
                *(half8*)&PH[r][q + 8] = *(half8*)&th[8];
            }
            { // stage C [128][64]
                int c = tid >> 1, hh = (tid & 1) * 32;
                const half8* ch = (const half8*)(chi + (size_t)(nt * 128 + c) * DDIM + ks * 64 + hh);
                const half8* cl = (const half8*)(clo + (size_t)(nt * 128 + c) * DDIM + ks * 64 + hh);
                #pragma unroll
                for (int i = 0; i < 4; ++i) {
                    *(half8*)&CH[c][hh + 8 * i] = ch[i];
                    *(half8*)&CL[c][hh + 8 * i] = cl[i];
                }
            }
            __syncthreads();

            #pragma unroll
            for (int kb = 0; kb < 2; ++kb) {
                const int k8 = kb * 32 + (lane >> 4) * 8;
                const int l15 = lane & 15;
                half8 aH[2], bH[4], bL[4];
                #pragma unroll
                for (int mi = 0; mi < 2; ++mi) {
                    int r = wr * 32 + mi * 16 + l15;
                    aH[mi] = *(half8*)&PH[r][k8];
                }
                #pragma unroll
                for (int ni = 0; ni < 4; ++ni) {
                    int c = wc * 64 + ni * 16 + l15;
                    bH[ni] = *(half8*)&CH[c][k8];
                    bL[ni] = *(half8*)&CL[c][k8];
                }
                #pragma unroll
                for (int mi = 0; mi < 2; ++mi)
                    #pragma unroll
                    for (int ni = 0; ni < 4; ++ni) {
                        acc1[mi][ni] = __builtin_amdgcn_mfma_f32_16x16x32_f16(aH[mi], bH[ni], acc1[mi][ni], 0, 0, 0);
                        acc2[mi][ni] = __builtin_amdgcn_mfma_f32_16x16x32_f16(aH[mi], bL[ni], acc2[mi][ni], 0, 0, 0);
                    }
            }
            __syncthreads();
        }

        #pragma unroll
        for (int ni = 0; ni < 4; ++ni) {
            int col = nt * 128 + wc * 64 + ni * 16 + (lane & 15);
            float cn = cn3[col];
            #pragma unroll
            for (int mi = 0; mi < 2; ++mi)
                #pragma unroll
                for (int j = 0; j < 4; ++j) {
                    float v = acc1[mi][ni][j] + acc2[mi][ni][j] * (1.0f / 2048.0f) - cn;
                    int s = mi * 4 + j;
                    if (v > v1[s])      { v2[s] = v1[s]; v1[s] = v; i1[s] = col; }
                    else if (v > v2[s]) { v2[s] = v; }
                }
        }
    }

    #pragma unroll
    for (int s = 0; s < 8; ++s) {
        float a1 = v1[s], a2 = v2[s];
        int ai = i1[s];
        #pragma unroll
        for (int m = 1; m < 16; m <<= 1) {
            float b1 = __shfl_xor(a1, m);
            float b2 = __shfl_xor(a2, m);
            int   bi = __shfl_xor(ai, m);
            float n2 = fmaxf(fminf(a1, b1), fmaxf(a2, b2));
            if (b1 > a1 || (b1 == a1 && bi < ai)) { a1 = b1; ai = bi; }
            a2 = n2;
        }
        v1[s] = a1; v2[s] = a2; i1[s] = ai;
    }
    if ((lane & 15) == 0) {
        #pragma unroll
        for (int s = 0; s < 8; ++s) {
            int mi = s >> 2, j = s & 3;
            int rloc = wr * 32 + mi * 16 + (lane >> 4) * 4 + j;
            mV1[rloc][wc] = v1[s]; mV2[rloc][wc] = v2[s];
            mI1[rloc][wc] = i1[s];
        }
    }
    __syncthreads();
    if (tid < 64) {
        float a1 = mV1[tid][0], a2 = mV2[tid][0], b1 = mV1[tid][1], b2 = mV2[tid][1];
        int ai = mI1[tid][0], bi = mI1[tid][1];
        float n2 = fmaxf(fminf(a1, b1), fmaxf(a2, b2));
        if (b1 > a1 || (b1 == a1 && bi < ai)) { a1 = b1; ai = bi; }
        out_idx[m0 + tid] = ai;
        if (a1 - n2 < TAU) {
            int slot = atomicAdd(fs_cnt, 1);
            fs_list[slot] = m0 + tid;
        }
    }
}

// ---------------------------------------------------------------- K3b: cb transpose (f32)
__global__ __launch_bounds__(256) void vq_transpose_cb(
    const float* __restrict__ cb, float* __restrict__ cbT)
{
    __shared__ float t[64][65];
    const int j0 = blockIdx.x * 64, d0 = blockIdx.y * 64;
    const int tid = threadIdx.x;
    for (int e = tid; e < 4096; e += 256) {
        int jr = e >> 6, dc = e & 63;
        t[jr][dc] = cb[(size_t)(j0 + jr) * DDIM + d0 + dc];
    }
    __syncthreads();
    for (int e = tid; e < 4096; e += 256) {
        int dr = e >> 6, jc = e & 63;
        cbT[(size_t)(d0 + dr) * KEMB + j0 + jc] = t[jc][dr];
    }
}

// ---------------------------------------------------------------- K4: np-exact rescan (reg-blocked)
__global__ __launch_bounds__(256) void vq_np_rescan(
    const float* __restrict__ pf, const float* __restrict__ cbT,
    const int* __restrict__ fs_list, const int* __restrict__ fs_cnt,
    int* __restrict__ out_idx)
{
    __shared__ float prow[RSB][DDIM];
    __shared__ float As[RSB];
    __shared__ float rD[RSB][4];
    __shared__ int   rJ[RSB][4];
    const int tid = threadIdx.x;
    const int lane = tid & 63;
    const int wv = tid >> 6;
    int cnt = *fs_cnt;
    if (cnt > ROWS) cnt = ROWS;

    for (int base = blockIdx.x * RSB; base < cnt; base += gridDim.x * RSB) {
        const int nr = min(RSB, cnt - base);
        __syncthreads();
        for (int i = tid; i < nr * 64; i += 256) {
            int r = i >> 6, q = (i & 63) * 4;
            *(float4*)&prow[r][q] =
                *(const float4*)&pf[(size_t)fs_list[base + r] * DDIM + q];
        }
        __syncthreads();
        if (tid < nr) As[tid] = np_sumsq_256(prow[tid]);
        __syncthreads();

        float bD[RSB]; int bJ[RSB];
        #pragma unroll
        for (int r = 0; r < RSB; ++r) { bD[r] = __builtin_inff(); bJ[r] = 0x7fffffff; }

        for (int sw = 0; sw < 4; ++sw) {
            const int j0 = sw * 1024 + tid * 4;
            float4 acc[RSB];
            #pragma unroll
            for (int r = 0; r < RSB; ++r) acc[r] = (float4){0.f, 0.f, 0.f, 0.f};
            for (int d4 = 0; d4 < DDIM / 4; ++d4) {
                float4 pv[RSB];
                #pragma unroll
                for (int r = 0; r < RSB; ++r)
                    pv[r] = *(const float4*)&prow[r][d4 * 4];
                #pragma unroll
                for (int dd = 0; dd < 4; ++dd) {
                    float4 cv = *(const float4*)&cbT[(size_t)(d4 * 4 + dd) * KEMB + j0];
                    #pragma unroll
                    for (int r = 0; r < RSB; ++r) {
                        float p = (dd == 0) ? pv[r].x : (dd == 1) ? pv[r].y
                                 : (dd == 2) ? pv[r].z : pv[r].w;
                        acc[r].x = __fmaf_rn(p, cv.x, acc[r].x);
                        acc[r].y = __fmaf_rn(p, cv.y, acc[r].y);
                        acc[r].z = __fmaf_rn(p, cv.z, acc[r].z);
                        acc[r].w = __fmaf_rn(p, cv.w, acc[r].w);
                    }
                }
            }
            #pragma unroll
            for (int r = 0; r < RSB; ++r) {
                float A = As[r];
                float D0 = fadd(A, fmul(-2.0f, acc[r].x));
                float D1 = fadd(A, fmul(-2.0f, acc[r].y));
                float D2 = fadd(A, fmul(-2.0f, acc[r].z));
                float D3 = fadd(A, fmul(-2.0f, acc[r].w));
                if (D0 < bD[r]) { bD[r] = D0; bJ[r] = j0; }
                if (D1 < bD[r]) { bD[r] = D1; bJ[r] = j0 + 1; }
                if (D2 < bD[r]) { bD[r] = D2; bJ[r] = j0 + 2; }
                if (D3 < bD[r]) { bD[r] = D3; bJ[r] = j0 + 3; }
            }
        }

        #pragma unroll
        for (int r = 0; r < RSB; ++r) {
            float d_ = bD[r]; int j_ = bJ[r];
            #pragma unroll
            for (int m = 1; m < 64; m <<= 1) {
                float od = __shfl_xor(d_, m);
                int   oj = __shfl_xor(j_, m);
                if (od < d_ || (od == d_ && oj < j_)) { d_ = od; j_ = oj; }
            }
            if (lane == 0) { rD[r][wv] = d_; rJ[r][wv] = j_; }
        }
        __syncthreads();
        if (tid < nr) {
            float d_ = rD[tid][0]; int j_ = rJ[tid][0];
            #pragma unroll
            for (int q = 1; q < 4; ++q) {
                float od = rD[tid][q]; int oj = rJ[tid][q];
                if (od < d_ || (od == d_ && oj < j_)) { d_ = od; j_ = oj; }
            }
            out_idx[fs_list[base + tid]] = j_;
        }
    }
}

// ---------------------------------------------------------------- K5: gather + loss partials
__global__ __launch_bounds__(256) void vq_gather(
    const float* __restrict__ cb, const float* __restrict__ pf,
    const int* __restrict__ idx,
    float* __restrict__ out0, float* __restrict__ outIdxF,
    float* __restrict__ partials)
{
    const int tid = threadIdx.x;
    const int lane = tid & 63;
    const int w = tid >> 6;
    const int row = blockIdx.x * 4 + w;
    const int k = idx[row];

    float4 c = *(const float4*)&cb[(size_t)k * DDIM + lane * 4];
    float4 p = *(const float4*)&pf[(size_t)row * DDIM + lane * 4];
    float d0 = c.x - p.x, d1 = c.y - p.y, d2 = c.z - p.z, d3 = c.w - p.w;
    float s = d0 * d0 + d1 * d1 + d2 * d2 + d3 * d3;

    *(float4*)&out0[(size_t)row * DDIM + lane * 4] = c;
    if (lane == 0) outIdxF[row] = (float)k;

    #pragma unroll
    for (int off = 32; off > 0; off >>= 1) s += __shfl_down(s, off);
    __shared__ float red[4];
    if (lane == 0) red[w] = s;
    __syncthreads();
    if (tid == 0) partials[blockIdx.x] = red[0] + red[1] + red[2] + red[3];
}

// ---------------------------------------------------------------- K6: loss reduce
__global__ __launch_bounds__(256) void vq_loss(
    const float* __restrict__ partials, float* __restrict__ out_loss)
{
    const int tid = threadIdx.x;
    float s = 0.f;
    for (int i = tid; i < ROWS / 4; i += 256) s += partials[i];
    #pragma unroll
    for (int off = 32; off > 0; off >>= 1) s += __shfl_down(s, off);
    __shared__ float red[4];
    if ((tid & 63) == 0) red[tid >> 6] = s;
    __syncthreads();
    if (tid == 0)
        out_loss[0] = 1.25f * (red[0] + red[1] + red[2] + red[3]) / 8388608.0f;
}

// ---------------------------------------------------------------- launch
extern "C" void kernel_launch(void* const* d_in, const int* in_sizes, int n_in,
                              void* d_out, int out_size, void* d_ws, size_t ws_size,
                              hipStream_t stream) {
    const float* feat = (const float*)d_in[0];
    const float* Wm   = (const float*)d_in[1];
    const float* bias = (const float*)d_in[2];
    const float* cb   = (const float*)d_in[3];

    char* ws = (char*)d_ws;
    float* pf       = (float*)(ws);               // 32 MiB
    f16*   chi      = (f16*)(ws + 33554432);      // 2 MiB  } dead after argmin;
    f16*   clo      = (f16*)(ws + 35651584);      // 2 MiB  } cbT overlays both
    float* cbT      = (float*)(ws + 33554432);    // 4 MiB f32 [256][4096]
    float* cn3      = (float*)(ws + 37748736);    // 16 KiB
    int*   idx      = (int*)(ws + 37765120);      // 128 KiB
    float* partials = (float*)(ws + 37896192);    // 32 KiB
    int*   fs_cnt   = (int*)(ws + 37928960);      // 128 B
    int*   fs_list  = (int*)(ws + 37929088);      // 128 KiB

    float* out0    = (float*)d_out;
    float* outLoss = (float*)d_out + 8388608;
    float* outIdxF = (float*)d_out + 8388609;

    hipMemsetAsync(fs_cnt, 0, 4, stream);
    vq_prep_codebook<<<KEMB, 256, 0, stream>>>(cb, chi, clo, cn3);
    vq_proj_np<<<ROWS / PRJ_R, 64, 0, stream>>>(feat, Wm, bias, pf);
    vq_argmin<<<ROWS / 64, 256, 0, stream>>>(pf, chi, clo, cn3, idx, fs_cnt, fs_list);
    vq_transpose_cb<<<dim3(KEMB / 64, DDIM / 64), 256, 0, stream>>>(cb, cbT);
    vq_np_rescan<<<512, 256, 0, stream>>>(pf, cbT, fs_list, fs_cnt, idx);
    vq_gather<<<ROWS / 4, 256, 0, stream>>>(cb, pf, idx, out0, outIdxF, partials);
    vq_loss<<<1, 256, 0, stream>>>(partials, outLoss);
}

// Round 8
// 1083.241 us; speedup vs baseline: 1.1240x; 1.1240x over previous
//
#include <hip/hip_runtime.h>

// VQ-VAE quantizer, MI355X (gfx950). Round 8: bit-exact np emulation (passing
// since r5). Proj v3: 2-wave blocks, 16 rows staged in LDS once; wave = 8 rows
// x 256 d (4 d/lane); W-chunk in regs reused across rows -> LDS:VALU = 0.19,
// VALU-bound. Scalar fmul/fadd in the exact np.einsum rounding order.
// argmin/transpose/rescan/gather/loss identical to rounds 6/7 (PASS twice).

typedef _Float16 f16;
typedef _Float16 half8 __attribute__((ext_vector_type(8)));
typedef float floatx4 __attribute__((ext_vector_type(4)));

#define ROWS   32768
#define IN_DIM 1024
#define DDIM   256
#define KEMB   4096
#define TAU    0.10f
#define RSB    8
#define PRJ_ROWS 16
#define PRJ_RW   8

__device__ __forceinline__ float fmul(float a, float b) { return __fmul_rn(a, b); }
__device__ __forceinline__ float fadd(float a, float b) { return __fadd_rn(a, b); }

__device__ __forceinline__ void split2(float x, f16& hi, f16& lo) {
    float h = (float)(f16)x;
    if (__builtin_fabsf(h) < 6.1035156e-5f) h = 0.0f;
    hi = (f16)h;
    lo = (f16)((x - h) * 2048.0f);
}

// np.sum(x*x) over 256 f32: pairwise 128+128; AVX512 vstep=16 block tree.
__device__ float np_sumsq_256(const float* __restrict__ x) {
    float blk[2];
    #pragma unroll
    for (int h = 0; h < 2; ++h) {
        const float* p = x + h * 128;
        float s[16];
        #pragma unroll
        for (int l = 0; l < 16; ++l) {
            float q0 = fmul(p[l],       p[l]);
            float q1 = fmul(p[16 + l],  p[16 + l]);
            float q2 = fmul(p[32 + l],  p[32 + l]);
            float q3 = fmul(p[48 + l],  p[48 + l]);
            float q4 = fmul(p[64 + l],  p[64 + l]);
            float q5 = fmul(p[80 + l],  p[80 + l]);
            float q6 = fmul(p[96 + l],  p[96 + l]);
            float q7 = fmul(p[112 + l], p[112 + l]);
            s[l] = fadd(fadd(fadd(q0, q1), fadd(q2, q3)),
                        fadd(fadd(q4, q5), fadd(q6, q7)));
        }
        float t1[8];
        #pragma unroll
        for (int l = 0; l < 8; ++l) t1[l] = fadd(s[l], s[l + 8]);
        float t2[4];
        #pragma unroll
        for (int l = 0; l < 4; ++l) t2[l] = fadd(t1[l], t1[l + 4]);
        blk[h] = fadd(fadd(t2[0], t2[2]), fadd(t2[1], t2[3]));
    }
    return fadd(blk[0], blk[1]);
}

// ---------------------------------------------------------------- K1: prep
__global__ __launch_bounds__(256) void vq_prep_codebook(
    const float* __restrict__ cb, f16* __restrict__ chi, f16* __restrict__ clo,
    float* __restrict__ cn3)
{
    int k = blockIdx.x;
    int d = threadIdx.x;
    float c = cb[(size_t)k * DDIM + d] * 4096.0f;
    f16 hi, lo;
    split2(c, hi, lo);
    chi[(size_t)k * DDIM + d] = hi;
    clo[(size_t)k * DDIM + d] = lo;
    float sq = c * c;
    #pragma unroll
    for (int off = 32; off > 0; off >>= 1) sq += __shfl_down(sq, off);
    __shared__ float red[4];
    if ((threadIdx.x & 63) == 0) red[threadIdx.x >> 6] = sq;
    __syncthreads();
    if (threadIdx.x == 0)
        cn3[k] = (red[0] + red[1] + red[2] + red[3]) * (1.0f / 8192.0f);
}

// ---------------------------------------------------------------- K2: proj (np.einsum emu, v3)
// Block: 128 threads (2 waves), 16 rows staged in LDS (64 KiB, loaded once).
// Wave wv owns rows wv*8..wv*8+7; lane owns d = lane + 64q (q=0..3).
// Per 16-k chunk: W (4dx16k) -> 16 float4 regs, reused over 8 rows; f row
// chunk -> 4 broadcast b128. Rounding chain per (d,row) identical to r5/r6:
// chunks ascending, within-chunk j=3..0, component-wise adds, hsum, +bias.
__global__ __launch_bounds__(128, 1) void vq_proj_np(
    const float* __restrict__ feat, const float* __restrict__ Wm,
    const float* __restrict__ bias, float* __restrict__ pf)
{
    __shared__ float fs[PRJ_ROWS][IN_DIM];   // 64 KiB
    const int r0 = blockIdx.x * PRJ_ROWS;
    const int tid = threadIdx.x;
    const int lane = tid & 63;
    const int wv = tid >> 6;

    { // stage 16 feature rows, coalesced
        const float4* src = (const float4*)(feat + (size_t)r0 * IN_DIM);
        float4* dst = (float4*)&fs[0][0];
        for (int i = tid; i < PRJ_ROWS * IN_DIM / 4; i += 128) dst[i] = src[i];
    }
    __syncthreads();

    const float* wp0 = Wm + (size_t)(lane      ) * IN_DIM;
    const float* wp1 = Wm + (size_t)(lane +  64) * IN_DIM;
    const float* wp2 = Wm + (size_t)(lane + 128) * IN_DIM;
    const float* wp3 = Wm + (size_t)(lane + 192) * IN_DIM;

    float4 acc[4][PRJ_RW];   // [q][r], 128 VGPRs
    #pragma unroll
    for (int q = 0; q < 4; ++q)
        #pragma unroll
        for (int r = 0; r < PRJ_RW; ++r)
            acc[q][r] = (float4){0.f, 0.f, 0.f, 0.f};

    #pragma unroll 1
    for (int c = 0; c < IN_DIM / 16; ++c) {
        const int ko = c * 16;
        float4 w[4][4];   // [q][j]
        #pragma unroll
        for (int j = 0; j < 4; ++j) {
            w[0][j] = *(const float4*)(wp0 + ko + j * 4);
            w[1][j] = *(const float4*)(wp1 + ko + j * 4);
            w[2][j] = *(const float4*)(wp2 + ko + j * 4);
            w[3][j] = *(const float4*)(wp3 + ko + j * 4);
        }
        #pragma unroll
        for (int r = 0; r < PRJ_RW; ++r) {
            const float* fr = &fs[wv * PRJ_RW + r][ko];
            float4 f0 = *(const float4*)(fr);
            float4 f1 = *(const float4*)(fr + 4);
            float4 f2 = *(const float4*)(fr + 8);
            float4 f3 = *(const float4*)(fr + 12);
            #pragma unroll
            for (int q = 0; q < 4; ++q) {
                float4 a = acc[q][r];
                a.x = fadd(a.x, fmul(f3.x, w[q][3].x));
                a.y = fadd(a.y, fmul(f3.y, w[q][3].y));
                a.z = fadd(a.z, fmul(f3.z, w[q][3].z));
                a.w = fadd(a.w, fmul(f3.w, w[q][3].w));
                a.x = fadd(a.x, fmul(f2.x, w[q][2].x));
                a.y = fadd(a.y, fmul(f2.y, w[q][2].y));
                a.z = fadd(a.z, fmul(f2.z, w[q][2].z));
                a.w = fadd(a.w, fmul(f2.w, w[q][2].w));
                a.x = fadd(a.x, fmul(f1.x, w[q][1].x));
                a.y = fadd(a.y, fmul(f1.y, w[q][1].y));
                a.z = fadd(a.z, fmul(f1.z, w[q][1].z));
                a.w = fadd(a.w, fmul(f1.w, w[q][1].w));
                a.x = fadd(a.x, fmul(f0.x, w[q][0].x));
                a.y = fadd(a.y, fmul(f0.y, w[q][0].y));
                a.z = fadd(a.z, fmul(f0.z, w[q][0].z));
                a.w = fadd(a.w, fmul(f0.w, w[q][0].w));
                acc[q][r] = a;
            }
        }
    }

    #pragma unroll
    for (int q = 0; q < 4; ++q) {
        const float bv = bias[lane + q * 64];
        #pragma unroll
        for (int r = 0; r < PRJ_RW; ++r) {
            float h = fadd(fadd(acc[q][r].x, acc[q][r].y),
                           fadd(acc[q][r].z, acc[q][r].w));
            pf[(size_t)(r0 + wv * PRJ_RW + r) * DDIM + lane + q * 64] = fadd(h, bv);
        }
    }
}

// ---------------------------------------------------------------- K3: MFMA argmin filter (2-pass)
__global__ __launch_bounds__(256) void vq_argmin(
    const float* __restrict__ pf,
    const f16* __restrict__ chi, const f16* __restrict__ clo,
    const float* __restrict__ cn3, int* __restrict__ out_idx,
    int* __restrict__ fs_cnt, int* __restrict__ fs_list)
{
    __shared__ f16 PH[64][72], CH[128][72], CL[128][72];
    __shared__ float mV1[64][2], mV2[64][2];
    __shared__ int   mI1[64][2];
    const int m0 = blockIdx.x * 64;
    const int tid = threadIdx.x;
    const int lane = tid & 63;
    const int w = tid >> 6;
    const int wr = w >> 1, wc = w & 1;

    float v1[8], v2[8];
    int i1[8];
    #pragma unroll
    for (int s = 0; s < 8; ++s) { v1[s] = -__builtin_inff(); v2[s] = -__builtin_inff(); i1[s] = 0; }

    for (int nt = 0; nt < KEMB / 128; ++nt) {
        floatx4 acc1[2][4], acc2[2][4];
        #pragma unroll
        for (int mi = 0; mi < 2; ++mi)
            #pragma unroll
            for (int ni = 0; ni < 4; ++ni) {
                acc1[mi][ni] = (floatx4){0.f, 0.f, 0.f, 0.f};
                acc2[mi][ni] = (floatx4){0.f, 0.f, 0.f, 0.f};
            }

        for (int ks = 0; ks < 4; ++ks) {
            { // stage P [64][64] hi-only, split on the fly
                int r = tid >> 2, q = (tid & 3) * 16;
                const float4* s4 = (const float4*)(pf + (size_t)(m0 + r) * DDIM + ks * 64 + q);
                f16 th[16];
                #pragma unroll
                for (int i = 0; i < 4; ++i) {
                    float4 v = s4[i];
                    f16 dead;
                    split2(v.x, th[4*i+0], dead);
                    split2(v.y, th[4*i+1], dead);
                    split2(v.z, th[4*i+2], dead);
                    split2(v.w, th[4*i+3], dead);
                }
                *(half8*)&PH[r][q]     = *(half8*)&th[0];
                *(half8*)&PH[r][q + 8] = *(half8*)&th[8];
            }
            { // stage C [128][64]
                int c = tid >> 1, hh = (tid & 1) * 32;
                const half8* ch = (const half8*)(chi + (size_t)(nt * 128 + c) * DDIM + ks * 64 + hh);
                const half8* cl = (const half8*)(clo + (size_t)(nt * 128 + c) * DDIM + ks * 64 + hh);
                #pragma unroll
                for (int i = 0; i < 4; ++i) {
                    *(half8*)&CH[c][hh + 8 * i] = ch[i];
                    *(half8*)&CL[c][hh + 8 * i] = cl[i];
                }
            }
            __syncthreads();

            #pragma unroll
            for (int kb = 0; kb < 2; ++kb) {
                const int k8 = kb * 32 + (lane >> 4) * 8;
                const int l15 = lane & 15;
                half8 aH[2], bH[4], bL[4];
                #pragma unroll
                for (int mi = 0; mi < 2; ++mi) {
                    int r = wr * 32 + mi * 16 + l15;
                    aH[mi] = *(half8*)&PH[r][k8];
                }
                #pragma unroll
                for (int ni = 0; ni < 4; ++ni) {
                    int c = wc * 64 + ni * 16 + l15;
                    bH[ni] = *(half8*)&CH[c][k8];
                    bL[ni] = *(half8*)&CL[c][k8];
                }
                #pragma unroll
                for (int mi = 0; mi < 2; ++mi)
                    #pragma unroll
                    for (int ni = 0; ni < 4; ++ni) {
                        acc1[mi][ni] = __builtin_amdgcn_mfma_f32_16x16x32_f16(aH[mi], bH[ni], acc1[mi][ni], 0, 0, 0);
                        acc2[mi][ni] = __builtin_amdgcn_mfma_f32_16x16x32_f16(aH[mi], bL[ni], acc2[mi][ni], 0, 0, 0);
                    }
            }
            __syncthreads();
        }

        #pragma unroll
        for (int ni = 0; ni < 4; ++ni) {
            int col = nt * 128 + wc * 64 + ni * 16 + (lane & 15);
            float cn = cn3[col];
            #pragma unroll
            for (int mi = 0; mi < 2; ++mi)
                #pragma unroll
                for (int j = 0; j < 4; ++j) {
                    float v = acc1[mi][ni][j] + acc2[mi][ni][j] * (1.0f / 2048.0f) - cn;
                    int s = mi * 4 + j;
                    if (v > v1[s])      { v2[s] = v1[s]; v1[s] = v; i1[s] = col; }
                    else if (v > v2[s]) { v2[s] = v; }
                }
        }
    }

    #pragma unroll
    for (int s = 0; s < 8; ++s) {
        float a1 = v1[s], a2 = v2[s];
        int ai = i1[s];
        #pragma unroll
        for (int m = 1; m < 16; m <<= 1) {
            float b1 = __shfl_xor(a1, m);
            float b2 = __shfl_xor(a2, m);
            int   bi = __shfl_xor(ai, m);
            float n2 = fmaxf(fminf(a1, b1), fmaxf(a2, b2));
            if (b1 > a1 || (b1 == a1 && bi < ai)) { a1 = b1; ai = bi; }
            a2 = n2;
        }
        v1[s] = a1; v2[s] = a2; i1[s] = ai;
    }
    if ((lane & 15) == 0) {
        #pragma unroll
        for (int s = 0; s < 8; ++s) {
            int mi = s >> 2, j = s & 3;
            int rloc = wr * 32 + mi * 16 + (lane >> 4) * 4 + j;
            mV1[rloc][wc] = v1[s]; mV2[rloc][wc] = v2[s];
            mI1[rloc][wc] = i1[s];
        }
    }
    __syncthreads();
    if (tid < 64) {
        float a1 = mV1[tid][0], a2 = mV2[tid][0], b1 = mV1[tid][1], b2 = mV2[tid][1];
        int ai = mI1[tid][0], bi = mI1[tid][1];
        float n2 = fmaxf(fminf(a1, b1), fmaxf(a2, b2));
        if (b1 > a1 || (b1 == a1 && bi < ai)) { a1 = b1; ai = bi; }
        out_idx[m0 + tid] = ai;
        if (a1 - n2 < TAU) {
            int slot = atomicAdd(fs_cnt, 1);
            fs_list[slot] = m0 + tid;
        }
    }
}

// ---------------------------------------------------------------- K3b: cb transpose (f32)
__global__ __launch_bounds__(256) void vq_transpose_cb(
    const float* __restrict__ cb, float* __restrict__ cbT)
{
    __shared__ float t[64][65];
    const int j0 = blockIdx.x * 64, d0 = blockIdx.y * 64;
    const int tid = threadIdx.x;
    for (int e = tid; e < 4096; e += 256) {
        int jr = e >> 6, dc = e & 63;
        t[jr][dc] = cb[(size_t)(j0 + jr) * DDIM + d0 + dc];
    }
    __syncthreads();
    for (int e = tid; e < 4096; e += 256) {
        int dr = e >> 6, jc = e & 63;
        cbT[(size_t)(d0 + dr) * KEMB + j0 + jc] = t[jc][dr];
    }
}

// ---------------------------------------------------------------- K4: np-exact rescan (reg-blocked)
__global__ __launch_bounds__(256) void vq_np_rescan(
    const float* __restrict__ pf, const float* __restrict__ cbT,
    const int* __restrict__ fs_list, const int* __restrict__ fs_cnt,
    int* __restrict__ out_idx)
{
    __shared__ float prow[RSB][DDIM];
    __shared__ float As[RSB];
    __shared__ float rD[RSB][4];
    __shared__ int   rJ[RSB][4];
    const int tid = threadIdx.x;
    const int lane = tid & 63;
    const int wv = tid >> 6;
    int cnt = *fs_cnt;
    if (cnt > ROWS) cnt = ROWS;

    for (int base = blockIdx.x * RSB; base < cnt; base += gridDim.x * RSB) {
        const int nr = min(RSB, cnt - base);
        __syncthreads();
        for (int i = tid; i < nr * 64; i += 256) {
            int r = i >> 6, q = (i & 63) * 4;
            *(float4*)&prow[r][q] =
                *(const float4*)&pf[(size_t)fs_list[base + r] * DDIM + q];
        }
        __syncthreads();
        if (tid < nr) As[tid] = np_sumsq_256(prow[tid]);
        __syncthreads();

        float bD[RSB]; int bJ[RSB];
        #pragma unroll
        for (int r = 0; r < RSB; ++r) { bD[r] = __builtin_inff(); bJ[r] = 0x7fffffff; }

        for (int sw = 0; sw < 4; ++sw) {
            const int j0 = sw * 1024 + tid * 4;
            float4 acc[RSB];
            #pragma unroll
            for (int r = 0; r < RSB; ++r) acc[r] = (float4){0.f, 0.f, 0.f, 0.f};
            for (int d4 = 0; d4 < DDIM / 4; ++d4) {
                float4 pv[RSB];
                #pragma unroll
                for (int r = 0; r < RSB; ++r)
                    pv[r] = *(const float4*)&prow[r][d4 * 4];
                #pragma unroll
                for (int dd = 0; dd < 4; ++dd) {
                    float4 cv = *(const float4*)&cbT[(size_t)(d4 * 4 + dd) * KEMB + j0];
                    #pragma unroll
                    for (int r = 0; r < RSB; ++r) {
                        float p = (dd == 0) ? pv[r].x : (dd == 1) ? pv[r].y
                                 : (dd == 2) ? pv[r].z : pv[r].w;
                        acc[r].x = __fmaf_rn(p, cv.x, acc[r].x);
                        acc[r].y = __fmaf_rn(p, cv.y, acc[r].y);
                        acc[r].z = __fmaf_rn(p, cv.z, acc[r].z);
                        acc[r].w = __fmaf_rn(p, cv.w, acc[r].w);
                    }
                }
            }
            #pragma unroll
            for (int r = 0; r < RSB; ++r) {
                float A = As[r];
                float D0 = fadd(A, fmul(-2.0f, acc[r].x));
                float D1 = fadd(A, fmul(-2.0f, acc[r].y));
                float D2 = fadd(A, fmul(-2.0f, acc[r].z));
                float D3 = fadd(A, fmul(-2.0f, acc[r].w));
                if (D0 < bD[r]) { bD[r] = D0; bJ[r] = j0; }
                if (D1 < bD[r]) { bD[r] = D1; bJ[r] = j0 + 1; }
                if (D2 < bD[r]) { bD[r] = D2; bJ[r] = j0 + 2; }
                if (D3 < bD[r]) { bD[r] = D3; bJ[r] = j0 + 3; }
            }
        }

        #pragma unroll
        for (int r = 0; r < RSB; ++r) {
            float d_ = bD[r]; int j_ = bJ[r];
            #pragma unroll
            for (int m = 1; m < 64; m <<= 1) {
                float od = __shfl_xor(d_, m);
                int   oj = __shfl_xor(j_, m);
                if (od < d_ || (od == d_ && oj < j_)) { d_ = od; j_ = oj; }
            }
            if (lane == 0) { rD[r][wv] = d_; rJ[r][wv] = j_; }
        }
        __syncthreads();
        if (tid < nr) {
            float d_ = rD[tid][0]; int j_ = rJ[tid][0];
            #pragma unroll
            for (int q = 1; q < 4; ++q) {
                float od = rD[tid][q]; int oj = rJ[tid][q];
                if (od < d_ || (od == d_ && oj < j_)) { d_ = od; j_ = oj; }
            }
            out_idx[fs_list[base + tid]] = j_;
        }
    }
}

// ---------------------------------------------------------------- K5: gather + loss partials
__global__ __launch_bounds__(256) void vq_gather(
    const float* __restrict__ cb, const float* __restrict__ pf,
    const int* __restrict__ idx,
    float* __restrict__ out0, float* __restrict__ outIdxF,
    float* __restrict__ partials)
{
    const int tid = threadIdx.x;
    const int lane = tid & 63;
    const int w = tid >> 6;
    const int row = blockIdx.x * 4 + w;
    const int k = idx[row];

    float4 c = *(const float4*)&cb[(size_t)k * DDIM + lane * 4];
    float4 p = *(const float4*)&pf[(size_t)row * DDIM + lane * 4];
    float d0 = c.x - p.x, d1 = c.y - p.y, d2 = c.z - p.z, d3 = c.w - p.w;
    float s = d0 * d0 + d1 * d1 + d2 * d2 + d3 * d3;

    *(float4*)&out0[(size_t)row * DDIM + lane * 4] = c;
    if (lane == 0) outIdxF[row] = (float)k;

    #pragma unroll
    for (int off = 32; off > 0; off >>= 1) s += __shfl_down(s, off);
    __shared__ float red[4];
    if (lane == 0) red[w] = s;
    __syncthreads();
    if (tid == 0) partials[blockIdx.x] = red[0] + red[1] + red[2] + red[3];
}

// ---------------------------------------------------------------- K6: loss reduce
__global__ __launch_bounds__(256) void vq_loss(
    const float* __restrict__ partials, float* __restrict__ out_loss)
{
    const int tid = threadIdx.x;
    float s = 0.f;
    for (int i = tid; i < ROWS / 4; i += 256) s += partials[i];
    #pragma unroll
    for (int off = 32; off > 0; off >>= 1) s += __shfl_down(s, off);
    __shared__ float red[4];
    if ((tid & 63) == 0) red[tid >> 6] = s;
    __syncthreads();
    if (tid == 0)
        out_loss[0] = 1.25f * (red[0] + red[1] + red[2] + red[3]) / 8388608.0f;
}

// ---------------------------------------------------------------- launch
extern "C" void kernel_launch(void* const* d_in, const int* in_sizes, int n_in,
                              void* d_out, int out_size, void* d_ws, size_t ws_size,
                              hipStream_t stream) {
    const float* feat = (const float*)d_in[0];
    const float* Wm   = (const float*)d_in[1];
    const float* bias = (const float*)d_in[2];
    const float* cb   = (const float*)d_in[3];

    char* ws = (char*)d_ws;
    float* pf       = (float*)(ws);               // 32 MiB
    f16*   chi      = (f16*)(ws + 33554432);      // 2 MiB  } dead after argmin;
    f16*   clo      = (f16*)(ws + 35651584);      // 2 MiB  } cbT overlays both
    float* cbT      = (float*)(ws + 33554432);    // 4 MiB f32 [256][4096]
    float* cn3      = (float*)(ws + 37748736);    // 16 KiB
    int*   idx      = (int*)(ws + 37765120);      // 128 KiB
    float* partials = (float*)(ws + 37896192);    // 32 KiB
    int*   fs_cnt   = (int*)(ws + 37928960);      // 128 B
    int*   fs_list  = (int*)(ws + 37929088);      // 128 KiB

    float* out0    = (float*)d_out;
    float* outLoss = (float*)d_out + 8388608;
    float* outIdxF = (float*)d_out + 8388609;

    hipMemsetAsync(fs_cnt, 0, 4, stream);
    vq_prep_codebook<<<KEMB, 256, 0, stream>>>(cb, chi, clo, cn3);
    vq_proj_np<<<ROWS / PRJ_ROWS, 128, 0, stream>>>(feat, Wm, bias, pf);
    vq_argmin<<<ROWS / 64, 256, 0, stream>>>(pf, chi, clo, cn3, idx, fs_cnt, fs_list);
    vq_transpose_cb<<<dim3(KEMB / 64, DDIM / 64), 256, 0, stream>>>(cb, cbT);
    vq_np_rescan<<<512, 256, 0, stream>>>(pf, cbT, fs_list, fs_cnt, idx);
    vq_gather<<<ROWS / 4, 256, 0, stream>>>(cb, pf, idx, out0, outIdxF, partials);
    vq_loss<<<1, 256, 0, stream>>>(partials, outLoss);
}

// Round 9
// 1073.629 us; speedup vs baseline: 1.1340x; 1.0090x over previous
//
#include <hip/hip_runtime.h>

// VQ-VAE quantizer, MI355X (gfx950). Round 9: bit-exact np emulation (passing
// since r5). Proj v4: NO LDS — 1-wave blocks, 8 rows/block, f rows read via
// wave-uniform loads (1 transaction/16B), W chunk in regs reused across rows.
// LDS=0 -> 2 waves/SIMD (was 1), stalls covered by co-resident wave.
// Same rounding chain as r5-r8. All other kernels identical to r6-r8 (PASS x3).

typedef _Float16 f16;
typedef _Float16 half8 __attribute__((ext_vector_type(8)));
typedef float floatx4 __attribute__((ext_vector_type(4)));

#define ROWS   32768
#define IN_DIM 1024
#define DDIM   256
#define KEMB   4096
#define TAU    0.10f
#define RSB    8
#define PRJ_RW 8

__device__ __forceinline__ float fmul(float a, float b) { return __fmul_rn(a, b); }
__device__ __forceinline__ float fadd(float a, float b) { return __fadd_rn(a, b); }

__device__ __forceinline__ void split2(float x, f16& hi, f16& lo) {
    float h = (float)(f16)x;
    if (__builtin_fabsf(h) < 6.1035156e-5f) h = 0.0f;
    hi = (f16)h;
    lo = (f16)((x - h) * 2048.0f);
}

// np.sum(x*x) over 256 f32: pairwise 128+128; AVX512 vstep=16 block tree.
__device__ float np_sumsq_256(const float* __restrict__ x) {
    float blk[2];
    #pragma unroll
    for (int h = 0; h < 2; ++h) {
        const float* p = x + h * 128;
        float s[16];
        #pragma unroll
        for (int l = 0; l < 16; ++l) {
            float q0 = fmul(p[l],       p[l]);
            float q1 = fmul(p[16 + l],  p[16 + l]);
            float q2 = fmul(p[32 + l],  p[32 + l]);
            float q3 = fmul(p[48 + l],  p[48 + l]);
            float q4 = fmul(p[64 + l],  p[64 + l]);
            float q5 = fmul(p[80 + l],  p[80 + l]);
            float q6 = fmul(p[96 + l],  p[96 + l]);
            float q7 = fmul(p[112 + l], p[112 + l]);
            s[l] = fadd(fadd(fadd(q0, q1), fadd(q2, q3)),
                        fadd(fadd(q4, q5), fadd(q6, q7)));
        }
        float t1[8];
        #pragma unroll
        for (int l = 0; l < 8; ++l) t1[l] = fadd(s[l], s[l + 8]);
        float t2[4];
        #pragma unroll
        for (int l = 0; l < 4; ++l) t2[l] = fadd(t1[l], t1[l + 4]);
        blk[h] = fadd(fadd(t2[0], t2[2]), fadd(t2[1], t2[3]));
    }
    return fadd(blk[0], blk[1]);
}

// ---------------------------------------------------------------- K1: prep
__global__ __launch_bounds__(256) void vq_prep_codebook(
    const float* __restrict__ cb, f16* __restrict__ chi, f16* __restrict__ clo,
    float* __restrict__ cn3)
{
    int k = blockIdx.x;
    int d = threadIdx.x;
    float c = cb[(size_t)k * DDIM + d] * 4096.0f;
    f16 hi, lo;
    split2(c, hi, lo);
    chi[(size_t)k * DDIM + d] = hi;
    clo[(size_t)k * DDIM + d] = lo;
    float sq = c * c;
    #pragma unroll
    for (int off = 32; off > 0; off >>= 1) sq += __shfl_down(sq, off);
    __shared__ float red[4];
    if ((threadIdx.x & 63) == 0) red[threadIdx.x >> 6] = sq;
    __syncthreads();
    if (threadIdx.x == 0)
        cn3[k] = (red[0] + red[1] + red[2] + red[3]) * (1.0f / 8192.0f);
}

// ---------------------------------------------------------------- K2: proj (np.einsum emu, v4)
// 64-thread (1-wave) blocks, 8 rows each. Lane owns d = lane + 64q (q=0..3).
// f loads are wave-uniform (blockIdx+loop only) -> 1 transaction each, no LDS.
// W chunk (4d x 16k) in 16 float4 regs, reused across the 8 rows.
// Rounding chain per (d,row) identical to r5-r8: chunks ascending, within-chunk
// j=3..0, per-component sequential adds, hsum (x+y)+(z+w), then +bias.
__global__ __launch_bounds__(64, 2) void vq_proj_np(
    const float* __restrict__ feat, const float* __restrict__ Wm,
    const float* __restrict__ bias, float* __restrict__ pf)
{
    const int r0 = blockIdx.x * PRJ_RW;
    const int lane = threadIdx.x;

    const float* wp0 = Wm + (size_t)(lane      ) * IN_DIM;
    const float* wp1 = Wm + (size_t)(lane +  64) * IN_DIM;
    const float* wp2 = Wm + (size_t)(lane + 128) * IN_DIM;
    const float* wp3 = Wm + (size_t)(lane + 192) * IN_DIM;

    float4 acc[4][PRJ_RW];   // [q][r] = 4 npyv sub-accumulators per output elem
    #pragma unroll
    for (int q = 0; q < 4; ++q)
        #pragma unroll
        for (int r = 0; r < PRJ_RW; ++r)
            acc[q][r] = (float4){0.f, 0.f, 0.f, 0.f};

    #pragma unroll 1
    for (int c = 0; c < IN_DIM / 16; ++c) {
        const int ko = c * 16;
        float4 w[4][4];   // [q][j]
        #pragma unroll
        for (int j = 0; j < 4; ++j) {
            w[0][j] = *(const float4*)(wp0 + ko + j * 4);
            w[1][j] = *(const float4*)(wp1 + ko + j * 4);
            w[2][j] = *(const float4*)(wp2 + ko + j * 4);
            w[3][j] = *(const float4*)(wp3 + ko + j * 4);
        }
        #pragma unroll
        for (int r = 0; r < PRJ_RW; ++r) {
            const float* fr = feat + (size_t)(r0 + r) * IN_DIM + ko;  // uniform
            float4 f0 = *(const float4*)(fr);
            float4 f1 = *(const float4*)(fr + 4);
            float4 f2 = *(const float4*)(fr + 8);
            float4 f3 = *(const float4*)(fr + 12);
            #pragma unroll
            for (int q = 0; q < 4; ++q) {
                float4 a = acc[q][r];
                a.x = fadd(a.x, fmul(f3.x, w[q][3].x));
                a.y = fadd(a.y, fmul(f3.y, w[q][3].y));
                a.z = fadd(a.z, fmul(f3.z, w[q][3].z));
                a.w = fadd(a.w, fmul(f3.w, w[q][3].w));
                a.x = fadd(a.x, fmul(f2.x, w[q][2].x));
                a.y = fadd(a.y, fmul(f2.y, w[q][2].y));
                a.z = fadd(a.z, fmul(f2.z, w[q][2].z));
                a.w = fadd(a.w, fmul(f2.w, w[q][2].w));
                a.x = fadd(a.x, fmul(f1.x, w[q][1].x));
                a.y = fadd(a.y, fmul(f1.y, w[q][1].y));
                a.z = fadd(a.z, fmul(f1.z, w[q][1].z));
                a.w = fadd(a.w, fmul(f1.w, w[q][1].w));
                a.x = fadd(a.x, fmul(f0.x, w[q][0].x));
                a.y = fadd(a.y, fmul(f0.y, w[q][0].y));
                a.z = fadd(a.z, fmul(f0.z, w[q][0].z));
                a.w = fadd(a.w, fmul(f0.w, w[q][0].w));
                acc[q][r] = a;
            }
        }
    }

    #pragma unroll
    for (int q = 0; q < 4; ++q) {
        const float bv = bias[lane + q * 64];
        #pragma unroll
        for (int r = 0; r < PRJ_RW; ++r) {
            float h = fadd(fadd(acc[q][r].x, acc[q][r].y),
                           fadd(acc[q][r].z, acc[q][r].w));
            pf[(size_t)(r0 + r) * DDIM + lane + q * 64] = fadd(h, bv);
        }
    }
}

// ---------------------------------------------------------------- K3: MFMA argmin filter (2-pass)
__global__ __launch_bounds__(256) void vq_argmin(
    const float* __restrict__ pf,
    const f16* __restrict__ chi, const f16* __restrict__ clo,
    const float* __restrict__ cn3, int* __restrict__ out_idx,
    int* __restrict__ fs_cnt, int* __restrict__ fs_list)
{
    __shared__ f16 PH[64][72], CH[128][72], CL[128][72];
    __shared__ float mV1[64][2], mV2[64][2];
    __shared__ int   mI1[64][2];
    const int m0 = blockIdx.x * 64;
    const int tid = threadIdx.x;
    const int lane = tid & 63;
    const int w = tid >> 6;
    const int wr = w >> 1, wc = w & 1;

    float v1[8], v2[8];
    int i1[8];
    #pragma unroll
    for (int s = 0; s < 8; ++s) { v1[s] = -__builtin_inff(); v2[s] = -__builtin_inff(); i1[s] = 0; }

    for (int nt = 0; nt < KEMB / 128; ++nt) {
        floatx4 acc1[2][4], acc2[2][4];
        #pragma unroll
        for (int mi = 0; mi < 2; ++mi)
            #pragma unroll
            for (int ni = 0; ni < 4; ++ni) {
                acc1[mi][ni] = (floatx4){0.f, 0.f, 0.f, 0.f};
                acc2[mi][ni] = (floatx4){0.f, 0.f, 0.f, 0.f};
            }

        for (int ks = 0; ks < 4; ++ks) {
            { // stage P [64][64] hi-only, split on the fly
                int r = tid >> 2, q = (tid & 3) * 16;
                const float4* s4 = (const float4*)(pf + (size_t)(m0 + r) * DDIM + ks * 64 + q);
                f16 th[16];
                #pragma unroll
                for (int i = 0; i < 4; ++i) {
                    float4 v = s4[i];
                    f16 dead;
                    split2(v.x, th[4*i+0], dead);
                    split2(v.y, th[4*i+1], dead);
                    split2(v.z, th[4*i+2], dead);
                    split2(v.w, th[4*i+3], dead);
                }
                *(half8*)&PH[r][q]     = *(half8*)&th[0];
                *(half8*)&PH[r][q + 8] = *(half8*)&th[8];
            }
            { // stage C [128][64]
                int c = tid >> 1, hh = (tid & 1) * 32;
                const half8* ch = (const half8*)(chi + (size_t)(nt * 128 + c) * DDIM + ks * 64 + hh);
                const half8* cl = (const half8*)(clo + (size_t)(nt * 128 + c) * DDIM + ks * 64 + hh);
                #pragma unroll
                for (int i = 0; i < 4; ++i) {
                    *(half8*)&CH[c][hh + 8 * i] = ch[i];
                    *(half8*)&CL[c][hh + 8 * i] = cl[i];
                }
            }
            __syncthreads();

            #pragma unroll
            for (int kb = 0; kb < 2; ++kb) {
                const int k8 = kb * 32 + (lane >> 4) * 8;
                const int l15 = lane & 15;
                half8 aH[2], bH[4], bL[4];
                #pragma unroll
                for (int mi = 0; mi < 2; ++mi) {
                    int r = wr * 32 + mi * 16 + l15;
                    aH[mi] = *(half8*)&PH[r][k8];
                }
                #pragma unroll
                for (int ni = 0; ni < 4; ++ni) {
                    int c = wc * 64 + ni * 16 + l15;
                    bH[ni] = *(half8*)&CH[c][k8];
                    bL[ni] = *(half8*)&CL[c][k8];
                }
                #pragma unroll
                for (int mi = 0; mi < 2; ++mi)
                    #pragma unroll
                    for (int ni = 0; ni < 4; ++ni) {
                        acc1[mi][ni] = __builtin_amdgcn_mfma_f32_16x16x32_f16(aH[mi], bH[ni], acc1[mi][ni], 0, 0, 0);
                        acc2[mi][ni] = __builtin_amdgcn_mfma_f32_16x16x32_f16(aH[mi], bL[ni], acc2[mi][ni], 0, 0, 0);
                    }
            }
            __syncthreads();
        }

        #pragma unroll
        for (int ni = 0; ni < 4; ++ni) {
            int col = nt * 128 + wc * 64 + ni * 16 + (lane & 15);
            float cn = cn3[col];
            #pragma unroll
            for (int mi = 0; mi < 2; ++mi)
                #pragma unroll
                for (int j = 0; j < 4; ++j) {
                    float v = acc1[mi][ni][j] + acc2[mi][ni][j] * (1.0f / 2048.0f) - cn;
                    int s = mi * 4 + j;
                    if (v > v1[s])      { v2[s] = v1[s]; v1[s] = v; i1[s] = col; }
                    else if (v > v2[s]) { v2[s] = v; }
                }
        }
    }

    #pragma unroll
    for (int s = 0; s < 8; ++s) {
        float a1 = v1[s], a2 = v2[s];
        int ai = i1[s];
        #pragma unroll
        for (int m = 1; m < 16; m <<= 1) {
            float b1 = __shfl_xor(a1, m);
            float b2 = __shfl_xor(a2, m);
            int   bi = __shfl_xor(ai, m);
            float n2 = fmaxf(fminf(a1, b1), fmaxf(a2, b2));
            if (b1 > a1 || (b1 == a1 && bi < ai)) { a1 = b1; ai = bi; }
            a2 = n2;
        }
        v1[s] = a1; v2[s] = a2; i1[s] = ai;
    }
    if ((lane & 15) == 0) {
        #pragma unroll
        for (int s = 0; s < 8; ++s) {
            int mi = s >> 2, j = s & 3;
            int rloc = wr * 32 + mi * 16 + (lane >> 4) * 4 + j;
            mV1[rloc][wc] = v1[s]; mV2[rloc][wc] = v2[s];
            mI1[rloc][wc] = i1[s];
        }
    }
    __syncthreads();
    if (tid < 64) {
        float a1 = mV1[tid][0], a2 = mV2[tid][0], b1 = mV1[tid][1], b2 = mV2[tid][1];
        int ai = mI1[tid][0], bi = mI1[tid][1];
        float n2 = fmaxf(fminf(a1, b1), fmaxf(a2, b2));
        if (b1 > a1 || (b1 == a1 && bi < ai)) { a1 = b1; ai = bi; }
        out_idx[m0 + tid] = ai;
        if (a1 - n2 < TAU) {
            int slot = atomicAdd(fs_cnt, 1);
            fs_list[slot] = m0 + tid;
        }
    }
}

// ---------------------------------------------------------------- K3b: cb transpose (f32)
__global__ __launch_bounds__(256) void vq_transpose_cb(
    const float* __restrict__ cb, float* __restrict__ cbT)
{
    __shared__ float t[64][65];
    const int j0 = blockIdx.x * 64, d0 = blockIdx.y * 64;
    const int tid = threadIdx.x;
    for (int e = tid; e < 4096; e += 256) {
        int jr = e >> 6, dc = e & 63;
        t[jr][dc] = cb[(size_t)(j0 + jr) * DDIM + d0 + dc];
    }
    __syncthreads();
    for (int e = tid; e < 4096; e += 256) {
        int dr = e >> 6, jc = e & 63;
        cbT[(size_t)(d0 + dr) * KEMB + j0 + jc] = t[jc][dr];
    }
}

// ---------------------------------------------------------------- K4: np-exact rescan (reg-blocked)
__global__ __launch_bounds__(256) void vq_np_rescan(
    const float* __restrict__ pf, const float* __restrict__ cbT,
    const int* __restrict__ fs_list, const int* __restrict__ fs_cnt,
    int* __restrict__ out_idx)
{
    __shared__ float prow[RSB][DDIM];
    __shared__ float As[RSB];
    __shared__ float rD[RSB][4];
    __shared__ int   rJ[RSB][4];
    const int tid = threadIdx.x;
    const int lane = tid & 63;
    const int wv = tid >> 6;
    int cnt = *fs_cnt;
    if (cnt > ROWS) cnt = ROWS;

    for (int base = blockIdx.x * RSB; base < cnt; base += gridDim.x * RSB) {
        const int nr = min(RSB, cnt - base);
        __syncthreads();
        for (int i = tid; i < nr * 64; i += 256) {
            int r = i >> 6, q = (i & 63) * 4;
            *(float4*)&prow[r][q] =
                *(const float4*)&pf[(size_t)fs_list[base + r] * DDIM + q];
        }
        __syncthreads();
        if (tid < nr) As[tid] = np_sumsq_256(prow[tid]);
        __syncthreads();

        float bD[RSB]; int bJ[RSB];
        #pragma unroll
        for (int r = 0; r < RSB; ++r) { bD[r] = __builtin_inff(); bJ[r] = 0x7fffffff; }

        for (int sw = 0; sw < 4; ++sw) {
            const int j0 = sw * 1024 + tid * 4;
            float4 acc[RSB];
            #pragma unroll
            for (int r = 0; r < RSB; ++r) acc[r] = (float4){0.f, 0.f, 0.f, 0.f};
            for (int d4 = 0; d4 < DDIM / 4; ++d4) {
                float4 pv[RSB];
                #pragma unroll
                for (int r = 0; r < RSB; ++r)
                    pv[r] = *(const float4*)&prow[r][d4 * 4];
                #pragma unroll
                for (int dd = 0; dd < 4; ++dd) {
                    float4 cv = *(const float4*)&cbT[(size_t)(d4 * 4 + dd) * KEMB + j0];
                    #pragma unroll
                    for (int r = 0; r < RSB; ++r) {
                        float p = (dd == 0) ? pv[r].x : (dd == 1) ? pv[r].y
                                 : (dd == 2) ? pv[r].z : pv[r].w;
                        acc[r].x = __fmaf_rn(p, cv.x, acc[r].x);
                        acc[r].y = __fmaf_rn(p, cv.y, acc[r].y);
                        acc[r].z = __fmaf_rn(p, cv.z, acc[r].z);
                        acc[r].w = __fmaf_rn(p, cv.w, acc[r].w);
                    }
                }
            }
            #pragma unroll
            for (int r = 0; r < RSB; ++r) {
                float A = As[r];
                float D0 = fadd(A, fmul(-2.0f, acc[r].x));
                float D1 = fadd(A, fmul(-2.0f, acc[r].y));
                float D2 = fadd(A, fmul(-2.0f, acc[r].z));
                float D3 = fadd(A, fmul(-2.0f, acc[r].w));
                if (D0 < bD[r]) { bD[r] = D0; bJ[r] = j0; }
                if (D1 < bD[r]) { bD[r] = D1; bJ[r] = j0 + 1; }
                if (D2 < bD[r]) { bD[r] = D2; bJ[r] = j0 + 2; }
                if (D3 < bD[r]) { bD[r] = D3; bJ[r] = j0 + 3; }
            }
        }

        #pragma unroll
        for (int r = 0; r < RSB; ++r) {
            float d_ = bD[r]; int j_ = bJ[r];
            #pragma unroll
            for (int m = 1; m < 64; m <<= 1) {
                float od = __shfl_xor(d_, m);
                int   oj = __shfl_xor(j_, m);
                if (od < d_ || (od == d_ && oj < j_)) { d_ = od; j_ = oj; }
            }
            if (lane == 0) { rD[r][wv] = d_; rJ[r][wv] = j_; }
        }
        __syncthreads();
        if (tid < nr) {
            float d_ = rD[tid][0]; int j_ = rJ[tid][0];
            #pragma unroll
            for (int q = 1; q < 4; ++q) {
                float od = rD[tid][q]; int oj = rJ[tid][q];
                if (od < d_ || (od == d_ && oj < j_)) { d_ = od; j_ = oj; }
            }
            out_idx[fs_list[base + tid]] = j_;
        }
    }
}

// ---------------------------------------------------------------- K5: gather + loss partials
__global__ __launch_bounds__(256) void vq_gather(
    const float* __restrict__ cb, const float* __restrict__ pf,
    const int* __restrict__ idx,
    float* __restrict__ out0, float* __restrict__ outIdxF,
    float* __restrict__ partials)
{
    const int tid = threadIdx.x;
    const int lane = tid & 63;
    const int w = tid >> 6;
    const int row = blockIdx.x * 4 + w;
    const int k = idx[row];

    float4 c = *(const float4*)&cb[(size_t)k * DDIM + lane * 4];
    float4 p = *(const float4*)&pf[(size_t)row * DDIM + lane * 4];
    float d0 = c.x - p.x, d1 = c.y - p.y, d2 = c.z - p.z, d3 = c.w - p.w;
    float s = d0 * d0 + d1 * d1 + d2 * d2 + d3 * d3;

    *(float4*)&out0[(size_t)row * DDIM + lane * 4] = c;
    if (lane == 0) outIdxF[row] = (float)k;

    #pragma unroll
    for (int off = 32; off > 0; off >>= 1) s += __shfl_down(s, off);
    __shared__ float red[4];
    if (lane == 0) red[w] = s;
    __syncthreads();
    if (tid == 0) partials[blockIdx.x] = red[0] + red[1] + red[2] + red[3];
}

// ---------------------------------------------------------------- K6: loss reduce
__global__ __launch_bounds__(256) void vq_loss(
    const float* __restrict__ partials, float* __restrict__ out_loss)
{
    const int tid = threadIdx.x;
    float s = 0.f;
    for (int i = tid; i < ROWS / 4; i += 256) s += partials[i];
    #pragma unroll
    for (int off = 32; off > 0; off >>= 1) s += __shfl_down(s, off);
    __shared__ float red[4];
    if ((tid & 63) == 0) red[tid >> 6] = s;
    __syncthreads();
    if (tid == 0)
        out_loss[0] = 1.25f * (red[0] + red[1] + red[2] + red[3]) / 8388608.0f;
}

// ---------------------------------------------------------------- launch
extern "C" void kernel_launch(void* const* d_in, const int* in_sizes, int n_in,
                              void* d_out, int out_size, void* d_ws, size_t ws_size,
                              hipStream_t stream) {
    const float* feat = (const float*)d_in[0];
    const float* Wm   = (const float*)d_in[1];
    const float* bias = (const float*)d_in[2];
    const float* cb   = (const float*)d_in[3];

    char* ws = (char*)d_ws;
    float* pf       = (float*)(ws);               // 32 MiB
    f16*   chi      = (f16*)(ws + 33554432);      // 2 MiB  } dead after argmin;
    f16*   clo      = (f16*)(ws + 35651584);      // 2 MiB  } cbT overlays both
    float* cbT      = (float*)(ws + 33554432);    // 4 MiB f32 [256][4096]
    float* cn3      = (float*)(ws + 37748736);    // 16 KiB
    int*   idx      = (int*)(ws + 37765120);      // 128 KiB
    float* partials = (float*)(ws + 37896192);    // 32 KiB
    int*   fs_cnt   = (int*)(ws + 37928960);      // 128 B
    int*   fs_list  = (int*)(ws + 37929088);      // 128 KiB

    float* out0    = (float*)d_out;
    float* outLoss = (float*)d_out + 8388608;
    float* outIdxF = (float*)d_out + 8388609;

    hipMemsetAsync(fs_cnt, 0, 4, stream);
    vq_prep_codebook<<<KEMB, 256, 0, stream>>>(cb, chi, clo, cn3);
    vq_proj_np<<<ROWS / PRJ_RW, 64, 0, stream>>>(feat, Wm, bias, pf);
    vq_argmin<<<ROWS / 64, 256, 0, stream>>>(pf, chi, clo, cn3, idx, fs_cnt, fs_list);
    vq_transpose_cb<<<dim3(KEMB / 64, DDIM / 64), 256, 0, stream>>>(cb, cbT);
    vq_np_rescan<<<512, 256, 0, stream>>>(pf, cbT, fs_list, fs_cnt, idx);
    vq_gather<<<ROWS / 4, 256, 0, stream>>>(cb, pf, idx, out0, outIdxF, partials);
    vq_loss<<<1, 256, 0, stream>>>(partials, outLoss);
}